// Round 1
// 169.341 us; speedup vs baseline: 1.4181x; 1.4181x over previous
//
#include <hip/hip_runtime.h>
#include <hip/hip_bf16.h>
#include <stdint.h>

// HMM batched forward, B=128, T=8192, S=65 (state 0 = bookend dead after init), V=1024.
//
// R18: swapped-operand MFMA removes the LDS C->A round trip from the serial
// chain. Compute C = A_ET^T x B_alpha (16x16x32 f16): C layout (proven) gives
// lane&15 = chain, rows 16u+4g+r over (lane>>4, reg) -- which IS the proven
// B-fragment placement (k = 16*up+4g+q at slot 2q+up). So MFMA output repacks
// into the next B operand with 8 v_cvt_pkrtz, zero cross-lane traffic.
// A operand = ET^T in the proven A layout (m=lane&15, k=16up+4(lane>>4)+q) --
// bit-identical to the existing gETB/tET table (frag_pos placement), so tET
// is reused unchanged. Emissions now per-lane-chain (c=lane&15, 16 states
// 16u+4g+{0..3}) from a NATURAL [v][s] table: 4x dwordx4 per stage at
// v*256B + 64u + 16g (16B chunks coalesce per v across g). Renorm: in-lane
// hsum + shfl_xor(16/32), stale-inv + counted-window log per chain --
// exactly the R15/16-verified bookkeeping, now scalar per lane. Ring: depth-2
// apps x 8 loads, vmcnt(8), unchanged. Q=32 segments of 128 apps + 96-app
// burn-in -> 224 serial apps, 256 blocks = 1 wave/CU.

#define HMM_B 128
#define HMM_T 8192
#define HMM_S 65
#define HMM_V 1024
#define LN2 0.6931471805599453
#define W_BURN 96
#define QSEG 32
#define SEGAPPS 128
#define NB 16
#define OPITCH 229

typedef _Float16 h8 __attribute__((ext_vector_type(8)));
typedef int    v4i __attribute__((ext_vector_type(4)));
typedef float  v4f __attribute__((ext_vector_type(4)));
typedef unsigned int uint;

// ---------------- device-global tables ----------------
__device__ __attribute__((aligned(16))) __fp16 gETB[4096];           // ET frag table (A role now)
__device__ __attribute__((aligned(16))) float  gEmitN[HMM_V * 64];   // NATURAL: [v][s] = e_v[s]
__device__ __attribute__((aligned(16))) float gArowN[64];            // natural: alpha0 row
__device__ __attribute__((aligned(16))) float gTcsN[64];             // natural: exp(tcol[s]-tcmax)
__device__ float gTcmax;
__device__ __attribute__((aligned(16))) float gVec[HMM_B * 64];      // final states, natural
__device__ __attribute__((aligned(16))) float gLsF[HMM_B * QSEG];

// frag-position (proven): value X[i][n] -> (r, lane, slot j). Serves BOTH the
// B-role (X=ET, B[k=i][n]) and, by the proven layout symmetry the R17 kernel
// already exercised on its A reads, the A-role (A=ET^T: A[m=n][k=i]).
__device__ __forceinline__ void frag_pos(int i, int n, int* r, int* lane, int* j) {
    int t = i >> 5, up = (i >> 4) & 1, g = (i & 15) >> 2, q = i & 3;
    *r = t * 4 + (n >> 4);
    *lane = g * 16 + (n & 15);
    *j = 2 * q + up;
}

// ---------------- helpers ----------------
__device__ __forceinline__ float fast_rcp(float x) {
#if __has_builtin(__builtin_amdgcn_rcpf)
    return __builtin_amdgcn_rcpf(x);
#else
    return 1.0f / x;
#endif
}
__device__ __forceinline__ h8 bfrag(v4i q) { return __builtin_bit_cast(h8, q); }
__device__ __forceinline__ int pkh(float a, float b) {
    return __builtin_bit_cast(int, __builtin_amdgcn_cvt_pkrtz(a, b));
}
__device__ __forceinline__ v4f vs(v4f a, float s) {
    return (v4f){a[0] * s, a[1] * s, a[2] * s, a[3] * s};
}

#define MFMA16(A, B, C) __builtin_amdgcn_mfma_f32_16x16x32_f16((A), (B), (C), 0, 0, 0)

// 8 MFMA, 4 independent accumulate-chains of depth 2 (C-in chaining).
// A = tET[t*4+u] (k-half t, out-block u), B = af0/af1 (alpha k-halves).
// Yu = out-states 16u+4g+r for chain lane&15.
#define MFMA_Y                                              \
    {                                                       \
        v4f z4v_ = {0.f, 0.f, 0.f, 0.f};                    \
        v4f D0_ = MFMA16(bfrag(tET[0]), af0, z4v_);         \
        v4f D1_ = MFMA16(bfrag(tET[1]), af0, z4v_);         \
        v4f D2_ = MFMA16(bfrag(tET[2]), af0, z4v_);         \
        v4f D3_ = MFMA16(bfrag(tET[3]), af0, z4v_);         \
        Y0 = MFMA16(bfrag(tET[4]), af1, D0_);               \
        Y1 = MFMA16(bfrag(tET[5]), af1, D1_);               \
        Y2 = MFMA16(bfrag(tET[6]), af1, D2_);                \
        Y3 = MFMA16(bfrag(tET[7]), af1, D3_);               \
    }

// C -> next B operand, in-register: slot 2q+up of k-half h <- Y_{2h+up}[q].
#define PACK_AF                                                                       \
    af0 = bfrag((v4i){pkh(z0[0], z1[0]), pkh(z0[1], z1[1]),                           \
                      pkh(z0[2], z1[2]), pkh(z0[3], z1[3])});                         \
    af1 = bfrag((v4i){pkh(z2[0], z3[0]), pkh(z2[1], z3[1]),                           \
                      pkh(z2[2], z3[2]), pkh(z2[3], z3[3])});

// per-chain sum over 64 states: in-lane 16 + reduce across the 4 g-lanes.
// Off the critical path (stale inv used next app).
#define RENORM(EI)                                          \
    {                                                       \
        v4f t_ = (z0 + z1) + (z2 + z3);                     \
        float s_ = (t_[0] + t_[1]) + (t_[2] + t_[3]);       \
        s_ += __shfl_xor(s_, 16);                           \
        s_ += __shfl_xor(s_, 32);                           \
        lsacc -= __log2f(EI);                               \
        inv = fast_rcp(s_);                                 \
    }

// one app = 2 stages; stale inv applied at stage A (R15 semantics, per chain)
#define APP8(EA0, EA1, EA2, EA3, EB0, EB1, EB2, EB3)                  \
    {                                                                 \
        float ei_ = inv;                                              \
        v4f M0_ = vs(EA0, ei_), M1_ = vs(EA1, ei_);                   \
        v4f M2_ = vs(EA2, ei_), M3_ = vs(EA3, ei_);                   \
        {                                                             \
            v4f Y0, Y1, Y2, Y3;                                       \
            MFMA_Y                                                    \
            z0 = Y0 * M0_; z1 = Y1 * M1_;                             \
            z2 = Y2 * M2_; z3 = Y3 * M3_;                             \
        }                                                             \
        PACK_AF                                                       \
        {                                                             \
            v4f Y0, Y1, Y2, Y3;                                       \
            MFMA_Y                                                    \
            z0 = Y0 * EB0; z1 = Y1 * EB1;                             \
            z2 = Y2 * EB2; z3 = Y3 * EB3;                             \
        }                                                             \
        PACK_AF                                                       \
        RENORM(ei_)                                                   \
    }

// half app (seg0 app0: one stage)
#define APP_HALF(E0, E1, E2, E3)                                      \
    {                                                                 \
        float ei_ = inv;                                              \
        {                                                             \
            v4f Y0, Y1, Y2, Y3;                                       \
            MFMA_Y                                                    \
            z0 = Y0 * vs(E0, ei_); z1 = Y1 * vs(E1, ei_);             \
            z2 = Y2 * vs(E2, ei_); z3 = Y3 * vs(E3, ei_);             \
        }                                                             \
        PACK_AF                                                       \
        RENORM(ei_)                                                   \
    }

// issue one app's 8 emission loads for this lane's chain (2 obs x 4 u-blocks)
#define ISSUE8(E0, E1, E2, E3, E4, E5, E6, E7, K)                                 \
    {                                                                             \
        uint w_ = obsw[cidx + (K)];                                               \
        uint a1_ = (w_ & 0xFFFFu) * 256u + gb;                                    \
        uint a2_ = (w_ >> 16) * 256u + gb;                                        \
        asm volatile("global_load_dwordx4 %0, %8, %10\n\t"                        \
                     "global_load_dwordx4 %1, %8, %10 offset:64\n\t"              \
                     "global_load_dwordx4 %2, %8, %10 offset:128\n\t"             \
                     "global_load_dwordx4 %3, %8, %10 offset:192\n\t"             \
                     "global_load_dwordx4 %4, %9, %10\n\t"                        \
                     "global_load_dwordx4 %5, %9, %10 offset:64\n\t"              \
                     "global_load_dwordx4 %6, %9, %10 offset:128\n\t"             \
                     "global_load_dwordx4 %7, %9, %10 offset:192"                 \
                     : "=&v"(E0), "=&v"(E1), "=&v"(E2), "=&v"(E3),                \
                       "=&v"(E4), "=&v"(E5), "=&v"(E6), "=&v"(E7)                 \
                     : "v"(a1_), "v"(a2_),                                        \
                       "s"((const float*)gEmitN)                                  \
                     : "memory");                                                 \
    }

#define WAITVA(E0, E1, E2, E3, E4, E5, E6, E7)                                    \
    asm volatile("s_waitcnt vmcnt(8)"                                             \
                 : "+v"(E0), "+v"(E1), "+v"(E2), "+v"(E3),                        \
                   "+v"(E4), "+v"(E5), "+v"(E6), "+v"(E7)                         \
                 :: "memory")

// ---------------- prep kernels ----------------
__global__ __launch_bounds__(256) void prep_emit(const float* __restrict__ log_emit) {
    int tid = blockIdx.x * 256 + threadIdx.x;  // 0..65535
    int j = tid >> 10;      // live state 0..63 (wave-uniform)
    int v = tid & 1023;     // consecutive -> coalesced reads
    gEmitN[v * 64 + j] = expf(log_emit[(j + 1) * HMM_V + v]);
}

__global__ __launch_bounds__(64) void prep_small(const float* __restrict__ log_trans,
                                                 const float* __restrict__ log_pi) {
    int j = threadIdx.x;  // live state j (output column)
    for (int i = 0; i < 64; ++i) {
        float et = expf(log_trans[(i + 1) * HMM_S + (j + 1)]);
        int r, lane, sj;
        frag_pos(i, j, &r, &lane, &sj);
        gETB[(r * 64 + lane) * 8 + sj] = (__fp16)(et * 16.0f);  // x16 f16-normal range
    }
    float s = 0.f;
    for (int i = 0; i < HMM_S; ++i)
        s += expf(log_pi[i]) * expf(log_trans[i * HMM_S + (j + 1)]);
    gArowN[j] = s;
    float tc = log_trans[(j + 1) * HMM_S + 0];
    float mx = tc;
    for (int d = 1; d < 64; d <<= 1) mx = fmaxf(mx, __shfl_xor(mx, d));
    gTcsN[j] = expf(tc - mx);
    if (j == 0) gTcmax = mx;
}

// ---------------- scan: 256 blocks = 8 batch-groups x 32 segments ----------------
__global__ __launch_bounds__(64, 1) void hmm_scan(const int* __restrict__ obvs) {
    __shared__ uint obsw[16 * OPITCH];                             // obs words
    const int bid = blockIdx.x;
    const int q = bid & (QSEG - 1);
    const int bg = bid >> 5;             // batch group 0..7 (chains = bg*16 + c)
    const int lane = threadIdx.x;
    const int g = lane >> 4;
    const int c = lane & 15;             // this lane's chain

    const int AstartFull = (q == 0) ? 0 : q * SEGAPPS - W_BURN;
    const int n4 = (q == 0) ? 64 : 112;  // int4 per chain
    const int nW = 2 * n4;               // words per chain

    // ---- stage obs words for 16 chains + 2 guard words each ----
    for (int cc = 0; cc < 16; ++cc) {
        const int4* og = (const int4*)(obvs + (size_t)(bg * 16 + cc) * HMM_T +
                                       (size_t)AstartFull * 2);
        for (int it = lane; it < n4; it += 64) {
            int4 o = og[it];
            obsw[cc * OPITCH + 2 * it]     = ((uint)o.x & 0xFFFFu) | ((uint)o.y << 16);
            obsw[cc * OPITCH + 2 * it + 1] = ((uint)o.z & 0xFFFFu) | ((uint)o.w << 16);
        }
        if (lane < 2) obsw[cc * OPITCH + nW + lane] = 0;
    }
    __syncthreads();

    // per-lane constants
    const uint gb = (uint)g * 16u;       // emission byte offset (4g floats)
    const int g4 = 4 * g;
    const int cidx = c * OPITCH;

    // ---- persistent ET fragments (32 VGPRs, table unchanged from R17) ----
    v4i tET[8];
    {
        const int4* tb = (const int4*)gETB;
#pragma unroll
        for (int r = 0; r < 8; ++r) {
            int4 t = tb[r * 64 + lane];
            tET[r] = (v4i){t.x, t.y, t.z, t.w};
        }
    }
    asm volatile("s_waitcnt vmcnt(0)"
                 : "+v"(tET[0]), "+v"(tET[1]), "+v"(tET[2]), "+v"(tET[3]),
                   "+v"(tET[4]), "+v"(tET[5]), "+v"(tET[6]), "+v"(tET[7])
                 :: "memory");

    float inv = 1.f, lsacc = 0.f;
    v4f z0, z1, z2, z3;
    h8 af0, af1;

    int kStart, kEnd, burnK;
    if (q == 0) {
        // ---- exact alpha0 init, normalized, then half app + app1 peel ----
        uint w0 = obsw[cidx + 0];
        {
            const float* e1 = gEmitN + (size_t)(w0 & 0xFFFFu) * 64 + g4;
            z0 = *(const v4f*)(gArowN + g4)      * *(const v4f*)(e1);
            z1 = *(const v4f*)(gArowN + 16 + g4) * *(const v4f*)(e1 + 16);
            z2 = *(const v4f*)(gArowN + 32 + g4) * *(const v4f*)(e1 + 32);
            z3 = *(const v4f*)(gArowN + 48 + g4) * *(const v4f*)(e1 + 48);
            v4f t_ = (z0 + z1) + (z2 + z3);
            float s_ = (t_[0] + t_[1]) + (t_[2] + t_[3]);
            s_ += __shfl_xor(s_, 16);
            s_ += __shfl_xor(s_, 32);
            float i_ = fast_rcp(s_);
            lsacc = -__log2f(i_);
            z0 = vs(z0, i_); z1 = vs(z1, i_);
            z2 = vs(z2, i_); z3 = vs(z3, i_);
        }
        PACK_AF
        // half app (covers step t=1), E = e(obs[1]) = word0 hi; inv==1
        {
            const float* e2 = gEmitN + (size_t)(w0 >> 16) * 64 + g4;
            v4f H0 = *(const v4f*)(e2);
            v4f H1 = *(const v4f*)(e2 + 16);
            v4f H2 = *(const v4f*)(e2 + 32);
            v4f H3 = *(const v4f*)(e2 + 48);
            APP_HALF(H0, H1, H2, H3)
        }
        // peeled app k=1 (direct loads)
        {
            uint w1 = obsw[cidx + 1];
            const float* p1 = gEmitN + (size_t)(w1 & 0xFFFFu) * 64 + g4;
            const float* p2 = gEmitN + (size_t)(w1 >> 16) * 64 + g4;
            v4f P0 = *(const v4f*)(p1),      P1 = *(const v4f*)(p1 + 16);
            v4f P2 = *(const v4f*)(p1 + 32), P3 = *(const v4f*)(p1 + 48);
            v4f P4 = *(const v4f*)(p2),      P5 = *(const v4f*)(p2 + 16);
            v4f P6 = *(const v4f*)(p2 + 32), P7 = *(const v4f*)(p2 + 48);
            APP8(P0, P1, P2, P3, P4, P5, P6, P7)
        }
        kStart = 2; kEnd = SEGAPPS; burnK = -1;
    } else {
        // uniform start; burn-in converges the direction
        z0 = z1 = z2 = z3 = (v4f){0.015625f, 0.015625f, 0.015625f, 0.015625f};
        PACK_AF
        kStart = 0; kEnd = SEGAPPS + W_BURN; burnK = W_BURN;
    }

    // ---- ring: depth 2 apps x 8 loads, wait vmcnt(8) ----
    v4f Ea0, Ea1, Ea2, Ea3, Ea4, Ea5, Ea6, Ea7;
    v4f Eb0, Eb1, Eb2, Eb3, Eb4, Eb5, Eb6, Eb7;
    ISSUE8(Ea0, Ea1, Ea2, Ea3, Ea4, Ea5, Ea6, Ea7, kStart)
    ISSUE8(Eb0, Eb1, Eb2, Eb3, Eb4, Eb5, Eb6, Eb7, kStart + 1)

    for (int a = kStart; a < kEnd; a += 2) {
        if (a == burnK) {  // cancel burn-in window (R15-verified mechanics)
            lsacc = __log2f(inv);
        }
        WAITVA(Ea0, Ea1, Ea2, Ea3, Ea4, Ea5, Ea6, Ea7);
        APP8(Ea0, Ea1, Ea2, Ea3, Ea4, Ea5, Ea6, Ea7)
        ISSUE8(Ea0, Ea1, Ea2, Ea3, Ea4, Ea5, Ea6, Ea7, a + 2)
        WAITVA(Eb0, Eb1, Eb2, Eb3, Eb4, Eb5, Eb6, Eb7);
        APP8(Eb0, Eb1, Eb2, Eb3, Eb4, Eb5, Eb6, Eb7)
        ISSUE8(Eb0, Eb1, Eb2, Eb3, Eb4, Eb5, Eb6, Eb7, a + 3)
    }
    asm volatile("s_waitcnt vmcnt(0)" ::: "memory");

    // ---- segment logs + handoff ----
    if (q != QSEG - 1) {  // pending last counted sum
        lsacc -= __log2f(inv);
    }
    // ET x16 repayment: 4/stage; counted stages: q0 = 255, else 256
    const float subf = (q == 0) ? 1020.0f : 1024.0f;
    if (lane < 16) {
        gLsF[(bg * 16 + lane) * QSEG + q] = (lsacc - subf) * (float)LN2;
    }
    if (q == QSEG - 1) {
        float* vp = gVec + (size_t)(bg * 16 + c) * 64 + g4;
        *(v4f*)(vp)      = z0;
        *(v4f*)(vp + 16) = z1;
        *(v4f*)(vp + 32) = z2;
        *(v4f*)(vp + 48) = z3;
    }
}

// ---------------- combine: out[b] = sum Dlog_q + tcmax + log(z_final . tau) ----------------
__global__ __launch_bounds__(64) void hmm_combine(float* __restrict__ out) {
    const int b = blockIdx.x;
    const int lane = threadIdx.x;
    float pr = gVec[b * 64 + lane] * gTcsN[lane];
#pragma unroll
    for (int d = 1; d < 64; d <<= 1) pr += __shfl_xor(pr, d);
    if (lane == 0) {
        double acc = 0.0;
#pragma unroll
        for (int k = 0; k < QSEG; ++k) acc += (double)gLsF[b * QSEG + k];
        out[b] = (float)(acc + (double)gTcmax + log((double)pr));
    }
}

// ---------------- launch ----------------
extern "C" void kernel_launch(void* const* d_in, const int* in_sizes, int n_in,
                              void* d_out, int out_size, void* d_ws, size_t ws_size,
                              hipStream_t stream) {
    const float* log_trans = (const float*)d_in[0];  // 65*65
    const float* log_emit  = (const float*)d_in[1];  // 65*1024
    const float* log_pi    = (const float*)d_in[2];  // 65
    const int*   obvs      = (const int*)d_in[3];    // 128*8192
    float* out = (float*)d_out;

    prep_emit<<<256, 256, 0, stream>>>(log_emit);
    prep_small<<<1, 64, 0, stream>>>(log_trans, log_pi);
    hmm_scan<<<QSEG * (HMM_B / NB), 64, 0, stream>>>(obvs);
    hmm_combine<<<HMM_B, 64, 0, stream>>>(out);
}